// Round 7
// baseline (568.849 us; speedup 1.0000x reference)
//
#include <hip/hip_runtime.h>

#define BB 1024
#define TT 512
#define KK 64
#define NEGV -10000.0f

// ---- DPP row-rotate helpers (row_ror:K within each 16-lane row) ----
template <int K>
static __device__ __forceinline__ float rorf(float x) {
    if constexpr (K == 0) {
        return x;
    } else {
        int i = __builtin_bit_cast(int, x);
        int r = __builtin_amdgcn_update_dpp(i, i, 0x120 + K, 0xF, 0xF, false);
        return __builtin_bit_cast(float, r);
    }
}
template <int K>
static __device__ __forceinline__ int rori(int x) {
    if constexpr (K == 0) return x;
    else return __builtin_amdgcn_update_dpp(x, x, 0x120 + K, 0xF, 0xF, false);
}
static __device__ __forceinline__ float fmax3(float a, float b, float c) {
    return fmaxf(fmaxf(a, b), c);   // fuses to v_max3_f32
}

// Viterbi row: 16 DPP-add candidates + max3 tree -> row max
#define VP(uj, J, K1, K2)                                                    \
    {                                                                        \
        float ca_ = rorf<K1>(uj) + trv[(J)*16 + (K1)];                       \
        float cb_ = rorf<K2>(uj) + trv[(J)*16 + (K2)];                       \
        rm_ = fmax3(rm_, ca_, cb_);                                          \
    }
#define VROW(uj, J, rmv)                                                     \
    {                                                                        \
        float rm_ = fmaxf(rorf<0>(uj) + trv[(J)*16 + 0],                     \
                          rorf<1>(uj) + trv[(J)*16 + 1]);                    \
        VP(uj, J, 2, 3) VP(uj, J, 4, 5) VP(uj, J, 6, 7) VP(uj, J, 8, 9)      \
        VP(uj, J, 10, 11) VP(uj, J, 12, 13) VP(uj, J, 14, 15)                \
        rmv = rm_;                                                           \
    }

// Forward row: 16 DPP-FMA into two alternating accumulators
#define FP(ej, J, K, acc) acc = fmaf(rorf<K>(ej), Er[(J)*16 + (K)], acc)
#define FROW(ej, J, accv)                                                    \
    {                                                                        \
        float aa_ = 0.f, ab_ = 0.f;                                          \
        FP(ej, J, 0, aa_);  FP(ej, J, 1, ab_);  FP(ej, J, 2, aa_);           \
        FP(ej, J, 3, ab_);  FP(ej, J, 4, aa_);  FP(ej, J, 5, ab_);           \
        FP(ej, J, 6, aa_);  FP(ej, J, 7, ab_);  FP(ej, J, 8, aa_);           \
        FP(ej, J, 9, ab_);  FP(ej, J, 10, aa_); FP(ej, J, 11, ab_);          \
        FP(ej, J, 12, aa_); FP(ej, J, 13, ab_); FP(ej, J, 14, ab_);          \
        FP(ej, J, 15, aa_);                                                  \
        accv = aa_ + ab_;                                                    \
    }

// Deferred argmax tail: descending exact-equality scan over the winning row
#define FINISH_TAIL(TROW)                                                    \
    {                                                                        \
        int bpv = p_base;                                                    \
        float vv;                                                            \
        vv = dwa3.w + dtg3.w; if (vv == p_m) bpv = p_base + 15;              \
        vv = dwa3.z + dtg3.z; if (vv == p_m) bpv = p_base + 14;              \
        vv = dwa3.y + dtg3.y; if (vv == p_m) bpv = p_base + 13;              \
        vv = dwa3.x + dtg3.x; if (vv == p_m) bpv = p_base + 12;              \
        vv = dwa2.w + dtg2.w; if (vv == p_m) bpv = p_base + 11;              \
        vv = dwa2.z + dtg2.z; if (vv == p_m) bpv = p_base + 10;              \
        vv = dwa2.y + dtg2.y; if (vv == p_m) bpv = p_base + 9;               \
        vv = dwa2.x + dtg2.x; if (vv == p_m) bpv = p_base + 8;               \
        vv = dwa1.w + dtg1.w; if (vv == p_m) bpv = p_base + 7;               \
        vv = dwa1.z + dtg1.z; if (vv == p_m) bpv = p_base + 6;               \
        vv = dwa1.y + dtg1.y; if (vv == p_m) bpv = p_base + 5;               \
        vv = dwa1.x + dtg1.x; if (vv == p_m) bpv = p_base + 4;               \
        vv = dwa0.w + dtg0.w; if (vv == p_m) bpv = p_base + 3;               \
        vv = dwa0.z + dtg0.z; if (vv == p_m) bpv = p_base + 2;               \
        vv = dwa0.y + dtg0.y; if (vv == p_m) bpv = p_base + 1;               \
        vv = dwa0.x + dtg0.x; if (vv == p_m) bpv = p_base + 0;               \
        bp[TROW][lane] = (unsigned char)bpv;                                 \
    }

// ---------------------------------------------------------------------------
// crf_kernel: one wave per batch; F and V merged. ALL per-step broadcasts via
// 3x shfl_xor + DPP row_ror fused into v_add/v_fmac (VALU) -- the 24 b128 LDS
// reads/step of R6 (the per-CU DS pipe was ~70% occupied = the bottleneck)
// are gone. LDS keeps only bp[] and a wa copy for the deferred argmax
// re-fetch. Viterbi stays bitwise-exact: same adds, order-independent maxes,
// (max, smallest-row) then descending in-row equality scan for first-index
// tie-breaks. DPP direction-proofing: prev indices are derived by pushing the
// lane index through the SAME DPP ops at init; tr/Er are gathered in that
// order, so the mapping is correct regardless of ror direction.
// ---------------------------------------------------------------------------
__global__ __launch_bounds__(64, 1) void crf_kernel(const float* __restrict__ feats,
                                                    const int* __restrict__ tags,
                                                    const float* __restrict__ trans,
                                                    float* __restrict__ out) {
    __shared__ unsigned char bp[TT][KK];        // 32 KB backpointers
    __shared__ __align__(16) float wa_buf[KK];  // viterbi alpha (for tail re-fetch)

    const int b = blockIdx.x;
    const int lane = threadIdx.x;

    // ---- gold score (one-time, lane-parallel gather) ----
    const int* tg = tags + (size_t)b * TT;
    float gold = 0.f;
#pragma unroll
    for (int i = 0; i < TT / 64; ++i) {
        int t = lane + i * 64;
        int nxt = tg[t];
        int prv = t ? tg[t - 1] : 0;
        gold += trans[nxt * KK + prv] + feats[((size_t)b * TT + t) * KK + nxt];
    }
    if (lane == 0) gold += trans[(KK - 1) * KK + tg[TT - 1]];  // STOP term
#pragma unroll
    for (int d = 1; d < 64; d <<= 1) gold += __shfl_xor(gold, d);

    // ---- rotation->prev index table (direction-proof by construction) ----
    int rot[16];
    rot[0] = lane;
    rot[1] = rori<1>(lane);   rot[2] = rori<2>(lane);   rot[3] = rori<3>(lane);
    rot[4] = rori<4>(lane);   rot[5] = rori<5>(lane);   rot[6] = rori<6>(lane);
    rot[7] = rori<7>(lane);   rot[8] = rori<8>(lane);   rot[9] = rori<9>(lane);
    rot[10] = rori<10>(lane); rot[11] = rori<11>(lane); rot[12] = rori<12>(lane);
    rot[13] = rori<13>(lane); rot[14] = rori<14>(lane); rot[15] = rori<15>(lane);

    // tr/Er in (row j, rotation k) order: candidate (j,k) pairs with
    // wa[prev], prev = rot[k] ^ (16*j).  (k-rotation preserves the 16-row.)
    float trv[KK];
    float Er[KK];
#pragma unroll
    for (int j = 0; j < 4; ++j) {
#pragma unroll
        for (int k = 0; k < 16; ++k) {
            int p = rot[k] ^ (j << 4);
            float tv = trans[lane * KK + p];
            trv[j * 16 + k] = tv;
            Er[j * 16 + k] = __expf(tv);
        }
    }
    const float t63 = trans[(KK - 1) * KK + lane];  // trans[STOP][lane]

    float a = (lane == 0) ? 0.f : NEGV;   // forward alpha (log domain)
    float w = a;                          // viterbi alpha (this lane's state)
    wa_buf[lane] = w;
    // pipelined wave-uniform normalizer: refUse(t) = shfl(a_{t-2}, 8) + 5
    float refUse = 0.f, refMid = 6.f, refNew = 12.f;

    // feats prefetch ring, depth 4
    const float* fbp = feats + (size_t)b * TT * KK + lane;
    float f0 = fbp[0 * KK];
    float f1 = fbp[1 * KK];
    float f2 = fbp[2 * KK];
    float f3 = fbp[3 * KK];
    const float* fp = fbp + 4 * KK;

    // pending (deferred) epilogue state for step t-1
    float4 dwa0 = {}, dwa1 = {}, dwa2 = {}, dwa3 = {};
    float4 dtg0 = {}, dtg1 = {}, dtg2 = {}, dtg3 = {};
    float p_m = 0.f;
    int p_base = 0;

    for (int t = 0; t < TT; ++t) {
        // ---- finish step t-1 (operands had a full iteration of cover) ----
        if (t) FINISH_TAIL(t - 1)

        const float f_cur = f0;
        f0 = f1; f1 = f2; f2 = f3;
        f3 = *fp;                       // row min(t+4, TT-1)
        if (t + 5 < TT) fp += KK;

        // ---- broadcast setup: 4 row-sources each for V and F ----
        const float u0 = w;
        const float e0 = __expf(a - refUse);
        const float u1 = __shfl_xor(u0, 16);
        const float u2 = __shfl_xor(u0, 32);
        const float u3 = __shfl_xor(u0, 48);
        const float e1 = __shfl_xor(e0, 16);
        const float e2 = __shfl_xor(e0, 32);
        const float e3 = __shfl_xor(e0, 48);

        // ---- viterbi: 64 DPP-add candidates, per-row maxima ----
        float rm0, rm1, rm2, rm3;
        VROW(u0, 0, rm0)
        VROW(u1, 1, rm1)
        VROW(u2, 2, rm2)
        VROW(u3, 3, rm3)

        // ---- forward: 64 DPP-FMA terms ----
        float fa0, fa1, fa2, fa3;
        FROW(e0, 0, fa0)
        FROW(e1, 1, fa1)
        FROW(e2, 2, fa2)
        FROW(e3, 3, fa3)
        float s = (fa0 + fa1) + (fa2 + fa3);
        float a_new = __logf(s) + refUse + f_cur;
        refUse = refMid;
        refMid = refNew;
        refNew = __shfl(a_new, 8) + 5.0f;   // consumed 2 iterations later
        a = a_new;

        // ---- row select: (max value, smallest absolute row) ----
        const int r0 = lane >> 4;
        float m = rm0;
        int br = r0;
        {
            int rr = r0 ^ 1;
            bool tk = (rm1 > m) || (rm1 == m && rr < br);
            m = tk ? rm1 : m; br = tk ? rr : br;
            rr = r0 ^ 2;
            tk = (rm2 > m) || (rm2 == m && rr < br);
            m = tk ? rm2 : m; br = tk ? rr : br;
            rr = r0 ^ 3;
            tk = (rm3 > m) || (rm3 == m && rr < br);
            m = tk ? rm3 : m; br = tk ? rr : br;
        }
        const int base = br << 4;
        const float w_new = m + f_cur;

        // issue deferred re-fetch of the winning row (consumed next iter);
        // LDS reads BEFORE the wa write -> in-order DS pipe sees old values
        {
            const float4* wam = reinterpret_cast<const float4*>(wa_buf + base);
            dwa0 = wam[0]; dwa1 = wam[1]; dwa2 = wam[2]; dwa3 = wam[3];
            wa_buf[lane] = w_new;
            const float4* trg = reinterpret_cast<const float4*>(trans + lane * KK + base);
            dtg0 = trg[0]; dtg1 = trg[1]; dtg2 = trg[2]; dtg3 = trg[3];
        }
        p_m = m;
        p_base = base;
        w = w_new;
    }
    // finish last step's bp
    FINISH_TAIL(TT - 1)

    // ---- forward score: exact logsumexp(alpha_T + trans[STOP][:]) ----
    float v = a + t63;
    float mm = v;
#pragma unroll
    for (int d = 32; d; d >>= 1) mm = fmaxf(mm, __shfl_xor(mm, d));
    float es = __expf(v - mm);
#pragma unroll
    for (int d = 32; d; d >>= 1) es += __shfl_xor(es, d);
    float fscore = mm + __logf(es);

    // ---- viterbi terminal: max + first-index argmax (exact) ----
    float tv = w + t63;
    float bvv = tv;
    int bidx = lane;
#pragma unroll
    for (int d = 1; d < 64; d <<= 1) {
        float ov = __shfl_xor(bvv, d);
        int oi = __shfl_xor(bidx, d);
        bool take = (ov > bvv) || (ov == bvv && oi < bidx);
        bvv = take ? ov : bvv;
        bidx = take ? oi : bidx;
    }

    if (lane == 0) {
        out[b] = fscore - gold;
        out[BB + b] = bvv;
    }

    // ---- backtrace: bulk LDS row loads + dynamic-shfl chain ----
    float* outp = out + 2 * BB + (size_t)b * TT;
    int cur = bidx;                 // wave-uniform
    float my = 0.f;                 // latched path values (lane = t & 63)
    for (int tb = TT - 16; tb >= 0; tb -= 16) {
        int r[16];
#pragma unroll
        for (int j = 0; j < 16; ++j) r[j] = bp[tb + j][lane];
#pragma unroll
        for (int j = 15; j >= 0; --j) {
            my = (lane == ((tb + j) & 63)) ? (float)cur : my;
            cur = __shfl(r[j], cur);
        }
        if ((tb & 63) == 0) outp[tb + lane] = my;   // coalesced 64-wide store
    }
}

extern "C" void kernel_launch(void* const* d_in, const int* in_sizes, int n_in,
                              void* d_out, int out_size, void* d_ws, size_t ws_size,
                              hipStream_t stream) {
    const float* feats = (const float*)d_in[0];
    const int* tags = (const int*)d_in[1];
    const float* trans = (const float*)d_in[2];
    float* out = (float*)d_out;

    crf_kernel<<<BB, 64, 0, stream>>>(feats, tags, trans, out);
}

// Round 8
// 474.473 us; speedup vs baseline: 1.1989x; 1.1989x over previous
//
#include <hip/hip_runtime.h>

#define BB 1024
#define TT 512
#define KK 64
#define NEGV -10000.0f

typedef _Float16 h2 __attribute__((ext_vector_type(2)));

#if defined(__has_builtin)
#if __has_builtin(__builtin_amdgcn_fdot2)
#define HAVE_FDOT2 1
#endif
#endif

static __device__ __forceinline__ float dot2_acc(h2 a, h2 b, float c) {
#ifdef HAVE_FDOT2
    return __builtin_amdgcn_fdot2(a, b, c, false);
#else
    return fmaf((float)a.x, (float)b.x, fmaf((float)a.y, (float)b.y, c));
#endif
}

static __device__ __forceinline__ h2 bc_h2(float f) {
    return __builtin_bit_cast(h2, f);
}

// prologue-only: lane-index pushed through the same DPP op (direction-proof)
template <int K>
static __device__ __forceinline__ int rori(int x) {
    if constexpr (K == 0) return x;
    else return __builtin_amdgcn_update_dpp(x, x, 0x120 + K, 0xF, 0xF, false);
}

// Fused DPP add: dst = row_ror<K>(src) + addend   (single v_add_f32_dpp)
#define VROT_(dst, src, addend, K)                                           \
    asm("v_add_f32_dpp %0, %1, %2 row_ror:" #K " row_mask:0xf bank_mask:0xf" \
        : "=v"(dst)                                                          \
        : "v"(src), "v"(addend))
#define VROT(dst, src, addend, K) VROT_(dst, src, addend, K)

// Viterbi row j: 16 fused DPP-add candidates + max3 tree -> row max
#define VROW(uj, J, rmv)                                                     \
    {                                                                        \
        float c1_, c2_, c3_, c4_, c5_, c6_, c7_, c8_;                        \
        float c9_, c10_, c11_, c12_, c13_, c14_, c15_;                       \
        float c0_ = (uj) + trv[(J) * 16 + 0];                                \
        VROT(c1_, uj, trv[(J) * 16 + 1], 1);                                 \
        VROT(c2_, uj, trv[(J) * 16 + 2], 2);                                 \
        VROT(c3_, uj, trv[(J) * 16 + 3], 3);                                 \
        VROT(c4_, uj, trv[(J) * 16 + 4], 4);                                 \
        VROT(c5_, uj, trv[(J) * 16 + 5], 5);                                 \
        VROT(c6_, uj, trv[(J) * 16 + 6], 6);                                 \
        VROT(c7_, uj, trv[(J) * 16 + 7], 7);                                 \
        VROT(c8_, uj, trv[(J) * 16 + 8], 8);                                 \
        VROT(c9_, uj, trv[(J) * 16 + 9], 9);                                 \
        VROT(c10_, uj, trv[(J) * 16 + 10], 10);                              \
        VROT(c11_, uj, trv[(J) * 16 + 11], 11);                              \
        VROT(c12_, uj, trv[(J) * 16 + 12], 12);                              \
        VROT(c13_, uj, trv[(J) * 16 + 13], 13);                              \
        VROT(c14_, uj, trv[(J) * 16 + 14], 14);                              \
        VROT(c15_, uj, trv[(J) * 16 + 15], 15);                              \
        float ma_ = fmaxf(fmaxf(fmaxf(c0_, c1_), fmaxf(c2_, c3_)),           \
                          fmaxf(fmaxf(c4_, c5_), fmaxf(c6_, c7_)));          \
        float mb_ = fmaxf(fmaxf(fmaxf(c8_, c9_), fmaxf(c10_, c11_)),         \
                          fmaxf(fmaxf(c12_, c13_), fmaxf(c14_, c15_)));      \
        rmv = fmaxf(ma_, mb_);                                               \
    }

// Deferred argmax tail: descending index-ordered equality scan (16-wide)
#define FINISH_TAIL(TROW)                                                    \
    {                                                                        \
        int bpv = p_base;                                                    \
        float vv;                                                            \
        vv = dwa3.w + dtg3.w; if (vv == p_m) bpv = p_base + 15;              \
        vv = dwa3.z + dtg3.z; if (vv == p_m) bpv = p_base + 14;              \
        vv = dwa3.y + dtg3.y; if (vv == p_m) bpv = p_base + 13;              \
        vv = dwa3.x + dtg3.x; if (vv == p_m) bpv = p_base + 12;              \
        vv = dwa2.w + dtg2.w; if (vv == p_m) bpv = p_base + 11;              \
        vv = dwa2.z + dtg2.z; if (vv == p_m) bpv = p_base + 10;              \
        vv = dwa2.y + dtg2.y; if (vv == p_m) bpv = p_base + 9;               \
        vv = dwa2.x + dtg2.x; if (vv == p_m) bpv = p_base + 8;               \
        vv = dwa1.w + dtg1.w; if (vv == p_m) bpv = p_base + 7;               \
        vv = dwa1.z + dtg1.z; if (vv == p_m) bpv = p_base + 6;               \
        vv = dwa1.y + dtg1.y; if (vv == p_m) bpv = p_base + 5;               \
        vv = dwa1.x + dtg1.x; if (vv == p_m) bpv = p_base + 4;               \
        vv = dwa0.w + dtg0.w; if (vv == p_m) bpv = p_base + 3;               \
        vv = dwa0.z + dtg0.z; if (vv == p_m) bpv = p_base + 2;               \
        vv = dwa0.y + dtg0.y; if (vv == p_m) bpv = p_base + 1;               \
        vv = dwa0.x + dtg0.x; if (vv == p_m) bpv = p_base + 0;               \
        bp[TROW][lane] = (unsigned char)bpv;                                 \
    }

// ---------------------------------------------------------------------------
// crf_kernel: one wave per batch, F+V merged.
//   V: broadcast via 3x shfl_xor + FUSED v_add_f32_dpp (asm) -- register-path
//      critical chain, no LDS broadcast. Row r = p-range [16r,16r+16);
//      (max, smallest-row) select; 16-wide index-ordered deferred tail
//      (wa_buf LDS + trans global re-fetch, one full step of latency cover).
//   F: R6-proven path (f16 ea_buf + 8x b128 + v_dot2, 2-deep pipelined ref).
// ---------------------------------------------------------------------------
__global__ __launch_bounds__(64, 1) void crf_kernel(const float* __restrict__ feats,
                                                    const int* __restrict__ tags,
                                                    const float* __restrict__ trans,
                                                    float* __restrict__ out) {
    __shared__ unsigned char bp[TT][KK];            // 32 KB backpointers
    __shared__ __align__(16) float wa_buf[KK];      // viterbi alpha (tail re-fetch)
    __shared__ __align__(16) _Float16 ea_buf[KK];   // exp(alpha - ref), f16

    const int b = blockIdx.x;
    const int lane = threadIdx.x;

    // ---- gold score (one-time, lane-parallel gather) ----
    const int* tg = tags + (size_t)b * TT;
    float gold = 0.f;
#pragma unroll
    for (int i = 0; i < TT / 64; ++i) {
        int t = lane + i * 64;
        int nxt = tg[t];
        int prv = t ? tg[t - 1] : 0;
        gold += trans[nxt * KK + prv] + feats[((size_t)b * TT + t) * KK + nxt];
    }
    if (lane == 0) gold += trans[(KK - 1) * KK + tg[TT - 1]];  // STOP term
#pragma unroll
    for (int d = 1; d < 64; d <<= 1) gold += __shfl_xor(gold, d);

    // ---- rotation->prev index table (prologue only) ----
    int rot[16];
    rot[0] = lane;
    rot[1] = rori<1>(lane);   rot[2] = rori<2>(lane);   rot[3] = rori<3>(lane);
    rot[4] = rori<4>(lane);   rot[5] = rori<5>(lane);   rot[6] = rori<6>(lane);
    rot[7] = rori<7>(lane);   rot[8] = rori<8>(lane);   rot[9] = rori<9>(lane);
    rot[10] = rori<10>(lane); rot[11] = rori<11>(lane); rot[12] = rori<12>(lane);
    rot[13] = rori<13>(lane); rot[14] = rori<14>(lane); rot[15] = rori<15>(lane);

    // trv rotation-ordered: candidate (j,k) = ror_k(u_j) + trv[j*16+k], pairs
    // with prev p = rot[k] ^ (j<<4); row index (lane>>4)^j = p-range/16.
    float trv[KK];
#pragma unroll
    for (int j = 0; j < 4; ++j)
#pragma unroll
        for (int k = 0; k < 16; ++k)
            trv[j * 16 + k] = trans[lane * KK + (rot[k] ^ (j << 4))];

    // Er_pk index-ordered f16 pairs for the forward dot2 (R6 path)
    h2 Er_pk[KK / 2];
    {
        const float4* trow = reinterpret_cast<const float4*>(trans + lane * KK);
#pragma unroll
        for (int i = 0; i < 16; ++i) {
            float4 v = trow[i];
            h2 lo, hi;
            lo.x = (_Float16)__expf(v.x); lo.y = (_Float16)__expf(v.y);
            hi.x = (_Float16)__expf(v.z); hi.y = (_Float16)__expf(v.w);
            Er_pk[2 * i] = lo;
            Er_pk[2 * i + 1] = hi;
        }
    }
    const float t63 = trans[(KK - 1) * KK + lane];  // trans[STOP][lane]

    float a = (lane == 0) ? 0.f : NEGV;   // forward alpha (log domain)
    float w = a;                          // viterbi alpha (lane = state)
    wa_buf[lane] = w;
    // pipelined wave-uniform normalizer: refUse(t) = shfl(a_{t-2}, 8) + 5
    float refUse = 0.f, refMid = 6.f, refNew = 12.f;

    // feats prefetch ring, depth 4
    const float* fbp = feats + (size_t)b * TT * KK + lane;
    float f0 = fbp[0 * KK];
    float f1 = fbp[1 * KK];
    float f2 = fbp[2 * KK];
    float f3 = fbp[3 * KK];
    const float* fp = fbp + 4 * KK;

    // pending (deferred) epilogue state for step t-1
    float4 dwa0 = {}, dwa1 = {}, dwa2 = {}, dwa3 = {};
    float4 dtg0 = {}, dtg1 = {}, dtg2 = {}, dtg3 = {};
    float p_m = 0.f;
    int p_base = 0;

    for (int t = 0; t < TT; ++t) {
        // ---- finish step t-1 (operands had a full iteration of cover) ----
        if (t) FINISH_TAIL(t - 1)

        const float f_cur = f0;
        f0 = f1; f1 = f2; f2 = f3;
        f3 = *fp;                       // row min(t+4, TT-1)
        if (t + 5 < TT) fp += KK;

        // ======== forward: publish normalized exp(alpha), f16 ========
        float x = fminf(a - refUse, 11.0f);     // e^11 < f16 max
        ea_buf[lane] = (_Float16)__expf(x);
        // single-wave block: in-order DS pipe, no barrier needed

        // ======== viterbi: row sources + fused DPP candidates ========
        const float u0 = w;
        const float u1 = __shfl_xor(u0, 16);
        const float u2 = __shfl_xor(u0, 32);
        const float u3 = __shfl_xor(u0, 48);

        float rm0, rm1, rm2, rm3;
        VROW(u0, 0, rm0)
        VROW(u1, 1, rm1)
        VROW(u2, 2, rm2)
        VROW(u3, 3, rm3)

        // ======== forward: dot-products over the broadcast (R6) ========
        const float4* eb = reinterpret_cast<const float4*>(ea_buf);
        float s0 = 0.f, s1 = 0.f, s2 = 0.f, s3 = 0.f;
        float s4 = 0.f, s5 = 0.f, s6 = 0.f, s7 = 0.f;
#pragma unroll
        for (int q = 0; q < 8; ++q) {
            float4 e4 = eb[q];
            float acc = 0.f;
            acc = dot2_acc(bc_h2(e4.x), Er_pk[4 * q + 0], acc);
            acc = dot2_acc(bc_h2(e4.y), Er_pk[4 * q + 1], acc);
            acc = dot2_acc(bc_h2(e4.z), Er_pk[4 * q + 2], acc);
            acc = dot2_acc(bc_h2(e4.w), Er_pk[4 * q + 3], acc);
            switch (q) {   // 8 independent chains
                case 0: s0 = acc; break; case 1: s1 = acc; break;
                case 2: s2 = acc; break; case 3: s3 = acc; break;
                case 4: s4 = acc; break; case 5: s5 = acc; break;
                case 6: s6 = acc; break; case 7: s7 = acc; break;
            }
        }
        float s = ((s0 + s1) + (s2 + s3)) + ((s4 + s5) + (s6 + s7));
        float a_new = __logf(s) + refUse + f_cur;
        refUse = refMid;
        refMid = refNew;
        refNew = __shfl(a_new, 8) + 5.0f;   // consumed 2 iterations later
        a = a_new;

        // ======== viterbi: (max, smallest absolute row) select ========
        const int r0 = lane >> 4;
        float m = rm0;
        int br = r0;
        {
            int rr = r0 ^ 1;
            bool tk = (rm1 > m) || (rm1 == m && rr < br);
            m = tk ? rm1 : m; br = tk ? rr : br;
            rr = r0 ^ 2;
            tk = (rm2 > m) || (rm2 == m && rr < br);
            m = tk ? rm2 : m; br = tk ? rr : br;
            rr = r0 ^ 3;
            tk = (rm3 > m) || (rm3 == m && rr < br);
            m = tk ? rm3 : m; br = tk ? rr : br;
        }
        const int base = br << 4;
        const float w_new = m + f_cur;

        // issue deferred re-fetch of the winning row (consumed next iter);
        // LDS reads BEFORE the wa write -> in-order DS pipe sees old values
        {
            const float4* wam = reinterpret_cast<const float4*>(wa_buf + base);
            dwa0 = wam[0]; dwa1 = wam[1]; dwa2 = wam[2]; dwa3 = wam[3];
            wa_buf[lane] = w_new;
            const float4* trg = reinterpret_cast<const float4*>(trans + lane * KK + base);
            dtg0 = trg[0]; dtg1 = trg[1]; dtg2 = trg[2]; dtg3 = trg[3];
        }
        p_m = m;
        p_base = base;
        w = w_new;
    }
    // finish last step's bp
    FINISH_TAIL(TT - 1)

    // ---- forward score: exact logsumexp(alpha_T + trans[STOP][:]) ----
    float v = a + t63;
    float mm = v;
#pragma unroll
    for (int d = 32; d; d >>= 1) mm = fmaxf(mm, __shfl_xor(mm, d));
    float es = __expf(v - mm);
#pragma unroll
    for (int d = 32; d; d >>= 1) es += __shfl_xor(es, d);
    float fscore = mm + __logf(es);

    // ---- viterbi terminal: max + first-index argmax (exact) ----
    float tv = w + t63;
    float bvv = tv;
    int bidx = lane;
#pragma unroll
    for (int d = 1; d < 64; d <<= 1) {
        float ov = __shfl_xor(bvv, d);
        int oi = __shfl_xor(bidx, d);
        bool take = (ov > bvv) || (ov == bvv && oi < bidx);
        bvv = take ? ov : bvv;
        bidx = take ? oi : bidx;
    }

    if (lane == 0) {
        out[b] = fscore - gold;
        out[BB + b] = bvv;
    }

    // ---- backtrace: bulk LDS row loads + dynamic-shfl chain ----
    float* outp = out + 2 * BB + (size_t)b * TT;
    int cur = bidx;                 // wave-uniform
    float my = 0.f;                 // latched path values (lane = t & 63)
    for (int tb = TT - 16; tb >= 0; tb -= 16) {
        int r[16];
#pragma unroll
        for (int j = 0; j < 16; ++j) r[j] = bp[tb + j][lane];
#pragma unroll
        for (int j = 15; j >= 0; --j) {
            my = (lane == ((tb + j) & 63)) ? (float)cur : my;
            cur = __shfl(r[j], cur);
        }
        if ((tb & 63) == 0) outp[tb + lane] = my;   // coalesced 64-wide store
    }
}

extern "C" void kernel_launch(void* const* d_in, const int* in_sizes, int n_in,
                              void* d_out, int out_size, void* d_ws, size_t ws_size,
                              hipStream_t stream) {
    const float* feats = (const float*)d_in[0];
    const int* tags = (const int*)d_in[1];
    const float* trans = (const float*)d_in[2];
    float* out = (float*)d_out;

    crf_kernel<<<BB, 64, 0, stream>>>(feats, tags, trans, out);
}

// Round 9
// 442.608 us; speedup vs baseline: 1.2852x; 1.0720x over previous
//
#include <hip/hip_runtime.h>

#define BB 1024
#define TT 512
#define KK 64
#define NEGV -10000.0f

typedef _Float16 h2 __attribute__((ext_vector_type(2)));

#if defined(__has_builtin)
#if __has_builtin(__builtin_amdgcn_fdot2)
#define HAVE_FDOT2 1
#endif
#endif

static __device__ __forceinline__ float dot2_acc(h2 a, h2 b, float c) {
#ifdef HAVE_FDOT2
    return __builtin_amdgcn_fdot2(a, b, c, false);
#else
    return fmaf((float)a.x, (float)b.x, fmaf((float)a.y, (float)b.y, c));
#endif
}

static __device__ __forceinline__ h2 bc_h2(float f) {
    return __builtin_bit_cast(h2, f);
}

// lane^16 exchange on the DS-swizzle path (immediate pattern, no addr VGPR)
static __device__ __forceinline__ float swz16(float x) {
    return __builtin_bit_cast(
        float, __builtin_amdgcn_ds_swizzle(__builtin_bit_cast(int, x), 0x401F));
}

// prologue-only: lane-index pushed through the same DPP op (direction-proof)
template <int K>
static __device__ __forceinline__ int rori(int x) {
    if constexpr (K == 0) return x;
    else return __builtin_amdgcn_update_dpp(x, x, 0x120 + K, 0xF, 0xF, false);
}

// Fused DPP add: dst = row_ror<K>(src) + addend   (single v_add_f32_dpp)
#define VROT_(dst, src, addend, K)                                           \
    asm("v_add_f32_dpp %0, %1, %2 row_ror:" #K " row_mask:0xf bank_mask:0xf" \
        : "=v"(dst)                                                          \
        : "v"(src), "v"(addend))
#define VROT(dst, src, addend, K) VROT_(dst, src, addend, K)

// Viterbi row j: 16 fused DPP-add candidates + max3-shaped tree -> row max
#define VROW(uj, J, rmv)                                                     \
    {                                                                        \
        float c1_, c2_, c3_, c4_, c5_, c6_, c7_, c8_;                        \
        float c9_, c10_, c11_, c12_, c13_, c14_, c15_;                       \
        float c0_ = (uj) + trv[(J) * 16 + 0];                                \
        VROT(c1_, uj, trv[(J) * 16 + 1], 1);                                 \
        VROT(c2_, uj, trv[(J) * 16 + 2], 2);                                 \
        VROT(c3_, uj, trv[(J) * 16 + 3], 3);                                 \
        VROT(c4_, uj, trv[(J) * 16 + 4], 4);                                 \
        VROT(c5_, uj, trv[(J) * 16 + 5], 5);                                 \
        VROT(c6_, uj, trv[(J) * 16 + 6], 6);                                 \
        VROT(c7_, uj, trv[(J) * 16 + 7], 7);                                 \
        VROT(c8_, uj, trv[(J) * 16 + 8], 8);                                 \
        VROT(c9_, uj, trv[(J) * 16 + 9], 9);                                 \
        VROT(c10_, uj, trv[(J) * 16 + 10], 10);                              \
        VROT(c11_, uj, trv[(J) * 16 + 11], 11);                              \
        VROT(c12_, uj, trv[(J) * 16 + 12], 12);                              \
        VROT(c13_, uj, trv[(J) * 16 + 13], 13);                              \
        VROT(c14_, uj, trv[(J) * 16 + 14], 14);                              \
        VROT(c15_, uj, trv[(J) * 16 + 15], 15);                              \
        float t0_ = fmaxf(fmaxf(c0_, c1_), c2_);   /* max3 shapes */         \
        float t1_ = fmaxf(fmaxf(c3_, c4_), c5_);                             \
        float t2_ = fmaxf(fmaxf(c6_, c7_), c8_);                             \
        float t3_ = fmaxf(fmaxf(c9_, c10_), c11_);                           \
        float t4_ = fmaxf(fmaxf(c12_, c13_), c14_);                          \
        rmv = fmaxf(fmaxf(fmaxf(t0_, t1_), t2_),                             \
                    fmaxf(fmaxf(t3_, t4_), c15_));                           \
    }

// Deferred argmax tail: descending index-ordered equality scan (16-wide)
#define FINISH_TAIL(TROW)                                                    \
    {                                                                        \
        int bpv = p_base;                                                    \
        float vv;                                                            \
        vv = dwa3.w + dtg3.w; if (vv == p_m) bpv = p_base + 15;              \
        vv = dwa3.z + dtg3.z; if (vv == p_m) bpv = p_base + 14;              \
        vv = dwa3.y + dtg3.y; if (vv == p_m) bpv = p_base + 13;              \
        vv = dwa3.x + dtg3.x; if (vv == p_m) bpv = p_base + 12;              \
        vv = dwa2.w + dtg2.w; if (vv == p_m) bpv = p_base + 11;              \
        vv = dwa2.z + dtg2.z; if (vv == p_m) bpv = p_base + 10;              \
        vv = dwa2.y + dtg2.y; if (vv == p_m) bpv = p_base + 9;               \
        vv = dwa2.x + dtg2.x; if (vv == p_m) bpv = p_base + 8;               \
        vv = dwa1.w + dtg1.w; if (vv == p_m) bpv = p_base + 7;               \
        vv = dwa1.z + dtg1.z; if (vv == p_m) bpv = p_base + 6;               \
        vv = dwa1.y + dtg1.y; if (vv == p_m) bpv = p_base + 5;               \
        vv = dwa1.x + dtg1.x; if (vv == p_m) bpv = p_base + 4;               \
        vv = dwa0.w + dtg0.w; if (vv == p_m) bpv = p_base + 3;               \
        vv = dwa0.z + dtg0.z; if (vv == p_m) bpv = p_base + 2;               \
        vv = dwa0.y + dtg0.y; if (vv == p_m) bpv = p_base + 1;               \
        vv = dwa0.x + dtg0.x; if (vv == p_m) bpv = p_base + 0;               \
        bp[TROW][lane] = (unsigned char)bpv;                                 \
    }

// ---------------------------------------------------------------------------
// crf_kernel: one wave per batch, F+V merged.
//   V: lean DPP path. Sources u0..u3 via ds_swizzle(^16)/shfl(^32); 60 fused
//      v_add_f32_dpp candidates; max3-shaped row trees; (max, smallest-row)
//      select; 16-wide index-ordered deferred tail (wa_buf LDS + trans global
//      re-fetch with a full step of latency cover). w's critical path is
//      register-only -- no LDS round trip.
//   F: R6-proven path (f16 ea_buf + 8x b128 + v_dot2, 2-deep pipelined ref);
//      its ea write->read RT hides under V's ~130-instr register compute.
// ---------------------------------------------------------------------------
__global__ __launch_bounds__(64, 1) void crf_kernel(const float* __restrict__ feats,
                                                    const int* __restrict__ tags,
                                                    const float* __restrict__ trans,
                                                    float* __restrict__ out) {
    __shared__ unsigned char bp[TT][KK];            // 32 KB backpointers
    __shared__ __align__(16) float wa_buf[KK];      // viterbi alpha (tail re-fetch)
    __shared__ __align__(16) _Float16 ea_buf[KK];   // exp(alpha - ref), f16

    const int b = blockIdx.x;
    const int lane = threadIdx.x;

    // ---- gold score (one-time, lane-parallel gather) ----
    const int* tg = tags + (size_t)b * TT;
    float gold = 0.f;
#pragma unroll
    for (int i = 0; i < TT / 64; ++i) {
        int t = lane + i * 64;
        int nxt = tg[t];
        int prv = t ? tg[t - 1] : 0;
        gold += trans[nxt * KK + prv] + feats[((size_t)b * TT + t) * KK + nxt];
    }
    if (lane == 0) gold += trans[(KK - 1) * KK + tg[TT - 1]];  // STOP term
#pragma unroll
    for (int d = 1; d < 64; d <<= 1) gold += __shfl_xor(gold, d);

    // ---- rotation->prev index table (prologue only) ----
    int rot[16];
    rot[0] = lane;
    rot[1] = rori<1>(lane);   rot[2] = rori<2>(lane);   rot[3] = rori<3>(lane);
    rot[4] = rori<4>(lane);   rot[5] = rori<5>(lane);   rot[6] = rori<6>(lane);
    rot[7] = rori<7>(lane);   rot[8] = rori<8>(lane);   rot[9] = rori<9>(lane);
    rot[10] = rori<10>(lane); rot[11] = rori<11>(lane); rot[12] = rori<12>(lane);
    rot[13] = rori<13>(lane); rot[14] = rori<14>(lane); rot[15] = rori<15>(lane);

    // trv rotation-ordered: candidate (j,k) = ror_k(u_j) + trv[j*16+k], pairs
    // with prev p = rot[k] ^ (j<<4); absolute row (lane>>4)^j = p/16.
    float trv[KK];
#pragma unroll
    for (int j = 0; j < 4; ++j)
#pragma unroll
        for (int k = 0; k < 16; ++k)
            trv[j * 16 + k] = trans[lane * KK + (rot[k] ^ (j << 4))];

    // Er_pk index-ordered f16 pairs for the forward dot2 (R6 path)
    h2 Er_pk[KK / 2];
    {
        const float4* trow = reinterpret_cast<const float4*>(trans + lane * KK);
#pragma unroll
        for (int i = 0; i < 16; ++i) {
            float4 v = trow[i];
            h2 lo, hi;
            lo.x = (_Float16)__expf(v.x); lo.y = (_Float16)__expf(v.y);
            hi.x = (_Float16)__expf(v.z); hi.y = (_Float16)__expf(v.w);
            Er_pk[2 * i] = lo;
            Er_pk[2 * i + 1] = hi;
        }
    }
    const float t63 = trans[(KK - 1) * KK + lane];  // trans[STOP][lane]

    float a = (lane == 0) ? 0.f : NEGV;   // forward alpha (log domain)
    float w = a;                          // viterbi alpha (lane = state)
    wa_buf[lane] = w;
    // pipelined wave-uniform normalizer: refUse(t) = shfl(a_{t-2}, 8) + 5
    float refUse = 0.f, refMid = 6.f, refNew = 12.f;

    // feats prefetch ring, depth 4
    const float* fbp = feats + (size_t)b * TT * KK + lane;
    float f0 = fbp[0 * KK];
    float f1 = fbp[1 * KK];
    float f2 = fbp[2 * KK];
    float f3 = fbp[3 * KK];
    const float* fp = fbp + 4 * KK;

    // pending (deferred) epilogue state for step t-1
    float4 dwa0 = {}, dwa1 = {}, dwa2 = {}, dwa3 = {};
    float4 dtg0 = {}, dtg1 = {}, dtg2 = {}, dtg3 = {};
    float p_m = 0.f;
    int p_base = 0;

    for (int t = 0; t < TT; ++t) {
        // ---- finish step t-1 (operands had a full iteration of cover) ----
        if (t) FINISH_TAIL(t - 1)

        const float f_cur = f0;
        f0 = f1; f1 = f2; f2 = f3;
        f3 = *fp;                       // row min(t+4, TT-1)
        if (t + 5 < TT) fp += KK;

        // ======== forward: publish normalized exp(alpha), f16 (early:
        //          the LDS round trip hides under V's register compute) ====
        float x = fminf(a - refUse, 11.0f);     // e^11 < f16 max
        ea_buf[lane] = (_Float16)__expf(x);
        // single-wave block: in-order DS pipe, no barrier needed

        // ======== viterbi: row sources (register path) ========
        const float u0 = w;
        const float u1 = swz16(u0);             // w[lane^16]
        const float u2 = __shfl_xor(u0, 32);    // w[lane^32]
        const float u3 = swz16(u2);             // w[lane^48]

        float rm0, rm1, rm2, rm3;
        VROW(u0, 0, rm0)
        VROW(u1, 1, rm1)
        VROW(u2, 2, rm2)
        VROW(u3, 3, rm3)

        // ======== forward: dot-products over the broadcast (R6) ========
        const float4* eb = reinterpret_cast<const float4*>(ea_buf);
        float s0 = 0.f, s1 = 0.f, s2 = 0.f, s3 = 0.f;
        float s4 = 0.f, s5 = 0.f, s6 = 0.f, s7 = 0.f;
#pragma unroll
        for (int q = 0; q < 8; ++q) {
            float4 e4 = eb[q];
            float acc = 0.f;
            acc = dot2_acc(bc_h2(e4.x), Er_pk[4 * q + 0], acc);
            acc = dot2_acc(bc_h2(e4.y), Er_pk[4 * q + 1], acc);
            acc = dot2_acc(bc_h2(e4.z), Er_pk[4 * q + 2], acc);
            acc = dot2_acc(bc_h2(e4.w), Er_pk[4 * q + 3], acc);
            switch (q) {   // 8 independent chains
                case 0: s0 = acc; break; case 1: s1 = acc; break;
                case 2: s2 = acc; break; case 3: s3 = acc; break;
                case 4: s4 = acc; break; case 5: s5 = acc; break;
                case 6: s6 = acc; break; case 7: s7 = acc; break;
            }
        }
        float s = ((s0 + s1) + (s2 + s3)) + ((s4 + s5) + (s6 + s7));
        float a_new = __logf(s) + refUse + f_cur;
        refUse = refMid;
        refMid = refNew;
        refNew = __shfl(a_new, 8) + 5.0f;   // consumed 2 iterations later
        a = a_new;

        // ======== viterbi: (max, smallest absolute row) select ========
        const int r0 = lane >> 4;
        float m = rm0;
        int br = r0;
        {
            int rr = r0 ^ 1;
            bool tk = (rm1 > m) || (rm1 == m && rr < br);
            m = tk ? rm1 : m; br = tk ? rr : br;
            rr = r0 ^ 2;
            tk = (rm2 > m) || (rm2 == m && rr < br);
            m = tk ? rm2 : m; br = tk ? rr : br;
            rr = r0 ^ 3;
            tk = (rm3 > m) || (rm3 == m && rr < br);
            m = tk ? rm3 : m; br = tk ? rr : br;
        }
        const int base = br << 4;
        const float w_new = m + f_cur;

        // issue deferred re-fetch of the winning row (consumed next iter);
        // LDS reads BEFORE the wa write -> in-order DS pipe sees old values
        {
            const float4* wam = reinterpret_cast<const float4*>(wa_buf + base);
            dwa0 = wam[0]; dwa1 = wam[1]; dwa2 = wam[2]; dwa3 = wam[3];
            wa_buf[lane] = w_new;
            const float4* trg = reinterpret_cast<const float4*>(trans + lane * KK + base);
            dtg0 = trg[0]; dtg1 = trg[1]; dtg2 = trg[2]; dtg3 = trg[3];
        }
        p_m = m;
        p_base = base;
        w = w_new;
    }
    // finish last step's bp
    FINISH_TAIL(TT - 1)

    // ---- forward score: exact logsumexp(alpha_T + trans[STOP][:]) ----
    float v = a + t63;
    float mm = v;
#pragma unroll
    for (int d = 32; d; d >>= 1) mm = fmaxf(mm, __shfl_xor(mm, d));
    float es = __expf(v - mm);
#pragma unroll
    for (int d = 32; d; d >>= 1) es += __shfl_xor(es, d);
    float fscore = mm + __logf(es);

    // ---- viterbi terminal: max + first-index argmax (exact) ----
    float tv = w + t63;
    float bvv = tv;
    int bidx = lane;
#pragma unroll
    for (int d = 1; d < 64; d <<= 1) {
        float ov = __shfl_xor(bvv, d);
        int oi = __shfl_xor(bidx, d);
        bool take = (ov > bvv) || (ov == bvv && oi < bidx);
        bvv = take ? ov : bvv;
        bidx = take ? oi : bidx;
    }

    if (lane == 0) {
        out[b] = fscore - gold;
        out[BB + b] = bvv;
    }

    // ---- backtrace: bulk LDS row loads + dynamic-shfl chain ----
    float* outp = out + 2 * BB + (size_t)b * TT;
    int cur = bidx;                 // wave-uniform
    float my = 0.f;                 // latched path values (lane = t & 63)
    for (int tb = TT - 16; tb >= 0; tb -= 16) {
        int r[16];
#pragma unroll
        for (int j = 0; j < 16; ++j) r[j] = bp[tb + j][lane];
#pragma unroll
        for (int j = 15; j >= 0; --j) {
            my = (lane == ((tb + j) & 63)) ? (float)cur : my;
            cur = __shfl(r[j], cur);
        }
        if ((tb & 63) == 0) outp[tb + lane] = my;   // coalesced 64-wide store
    }
}

extern "C" void kernel_launch(void* const* d_in, const int* in_sizes, int n_in,
                              void* d_out, int out_size, void* d_ws, size_t ws_size,
                              hipStream_t stream) {
    const float* feats = (const float*)d_in[0];
    const int* tags = (const int*)d_in[1];
    const float* trans = (const float*)d_in[2];
    float* out = (float*)d_out;

    crf_kernel<<<BB, 64, 0, stream>>>(feats, tags, trans, out);
}